// Round 3
// baseline (1695.507 us; speedup 1.0000x reference)
//
#include <hip/hip_runtime.h>
#include <math.h>

#define BATCH 8
#define N_PTS 4096
#define KNN 20
#define EPS_BN 1e-5f
#define SLOPE 0.2f
#define M_ROWS (BATCH * N_PTS)
#define NSPLIT 2
#define CHALF (N_PTS / NSPLIT)

typedef __attribute__((ext_vector_type(8))) short short8;      // bf16 x8 (4 VGPR)
typedef __attribute__((ext_vector_type(2))) float float2v;     // fp32 x2
typedef __attribute__((ext_vector_type(4))) float float4v;     // fp32 x4 acc
typedef __attribute__((ext_vector_type(16))) float float16v;   // fp32 x16 acc

__device__ __forceinline__ unsigned short f2bf(float f) {
    unsigned u = __float_as_uint(f);
    unsigned r = (u + 0x7FFFu + ((u >> 16) & 1u)) >> 16;
    return (unsigned short)r;
}
__device__ __forceinline__ float bf2f(unsigned short h) {
    return __uint_as_float((unsigned)h << 16);
}

// ---------------------------------------------------------------------------
// x (B,3,N) fp32 -> x1h/x1l (M,32) bf16 split (zero-padded), + sq norms
__global__ void convert_x1(const float* __restrict__ x,
                           unsigned short* __restrict__ xh, unsigned short* __restrict__ xl,
                           float* __restrict__ sq) {
    int i = blockIdx.x * blockDim.x + threadIdx.x;
    if (i >= M_ROWS) return;
    int b = i / N_PTS, n = i % N_PTS;
    float v[3], s = 0.f;
    #pragma unroll
    for (int d = 0; d < 3; ++d) {
        v[d] = x[((size_t)b * 3 + d) * N_PTS + n];
        s += v[d] * v[d];
    }
    sq[i] = s;
    #pragma unroll
    for (int d = 0; d < 32; ++d) {
        float f = (d < 3) ? v[d] : 0.f;
        unsigned short h = f2bf(f);
        xh[(size_t)i * 32 + d] = h;
        xl[(size_t)i * 32 + d] = f2bf(f - bf2f(h));
    }
}

// sq norms from bf16 hi/lo feature rows (stride 512)
__global__ void sqnorm_hl(const unsigned short* __restrict__ hh,
                          const unsigned short* __restrict__ hl,
                          int D, float* __restrict__ sq) {
    int w = threadIdx.x >> 6, lane = threadIdx.x & 63;
    int row = blockIdx.x * 4 + w;
    if (row >= M_ROWS) return;
    const unsigned short* ph = hh + (size_t)row * 512;
    const unsigned short* pl = hl + (size_t)row * 512;
    float s = 0.f;
    for (int d = lane; d < D; d += 64) {
        float v = bf2f(ph[d]) + bf2f(pl[d]);
        s += v * v;
    }
    #pragma unroll
    for (int off = 32; off > 0; off >>= 1) s += __shfl_down(s, off, 64);
    if (lane == 0) sq[row] = s;
}

// ---------------------------------------------------------------------------
// weight repacks -> bf16 hi/lo, B-operand layout [C][KP] (k contiguous)
__global__ void repack_edge_split(const float* __restrict__ W, int Co, int D, int KP,
                                  unsigned short* __restrict__ Wh, unsigned short* __restrict__ Wl) {
    int i = blockIdx.x * blockDim.x + threadIdx.x;
    int tot = 2 * Co * KP;
    if (i >= tot) return;
    int r = i / KP, d = i % KP;
    float v = 0.f;
    if (d < D) v = (r < Co) ? W[(size_t)r * 2 * D + d] : W[(size_t)(r - Co) * 2 * D + D + d];
    unsigned short h = f2bf(v);
    Wh[i] = h; Wl[i] = f2bf(v - bf2f(h));
}

__global__ void repack_w5_split(const float* __restrict__ W,
                                unsigned short* __restrict__ Wh, unsigned short* __restrict__ Wl) {
    int i = blockIdx.x * blockDim.x + threadIdx.x;
    if (i >= 512 * 512) return;
    float v = W[i];
    unsigned short h = f2bf(v);
    Wh[i] = h; Wl[i] = f2bf(v - bf2f(h));
}

// ---------------------------------------------------------------------------
// MFMA KNN v9: v6 inner structure (3 barriers, VGPR staging, 1 acc chain) +
// candidate-dimension split x2 for occupancy (2 -> 4 blocks/CU; the
// latency/stall structure at 2 waves/SIMD was insensitive to all per-wave
// work reductions in v7/v8). Each block scans 2048 candidates, emits a
// sorted partial top-20 per row; knn_merge combines the two halves
// ((val,idx) lex over disjoint ranges == unsplit result exactly).
// Kept from v8 (measured-cheap): widened swizzle key (conflicts -2.7x),
// b64 selection reads (Sf stride 66). Kept from v7: exact shared-row
// threshold (deterministic here: publish/read separated by two barriers).
// grid: (N/64, B, NSPLIT), block 256.
template<int DPAD>
__launch_bounds__(256, 2)
__global__ void knn_mfma(const unsigned short* __restrict__ Xh,
                         const unsigned short* __restrict__ Xl,
                         int strideX,
                         const float* __restrict__ sq,
                         float* __restrict__ pv, int* __restrict__ pi) {
    constexpr int KS16 = DPAD / 16;           // mfma k-steps (K=16)
    constexpr int C8   = DPAD / 8;            // 16B chunks per col
    constexpr int XK   = (C8 - 1) < 15 ? (C8 - 1) : 15;  // xor swizzle key mask
    constexpr int SB   = 64 * DPAD;           // ushorts per stage buffer
    constexpr int NIT  = (64 * C8) / 256;     // staging iters (exact multiple)
    constexpr size_t STAGE = (size_t)2 * SB * 2 + (size_t)64 * 66 * 4 + 64 * 4 + 256 * 4;
    constexpr size_t MERGE = (size_t)64 * 61 * 4 * 2;
    constexpr size_t POOL  = STAGE > MERGE ? STAGE : MERGE;
    __shared__ __align__(16) char smem[POOL];
    unsigned short* BhS = (unsigned short*)smem;
    unsigned short* BlS = BhS + SB;
    float* Sf  = (float*)(smem + (size_t)2 * SB * 2);   // [64 rows][66] scores
    float* sqs = Sf + 64 * 66;
    float* thrT = sqs + 64;                             // [4][64] published fv[19]
    float*    kb = (float*)smem;                        // merge: [64][61] vals
    unsigned* ib = (unsigned*)(kb + 64 * 61);           //        [64][61] idx

    const int b = blockIdx.y;
    const int row0 = blockIdx.x * 64;
    const int sidx = blockIdx.z;
    const int cs0 = sidx * CHALF;
    const int tid = threadIdx.x;
    const int w = tid >> 6, lane = tid & 63;
    const int l31 = lane & 31, lh = lane >> 5;
    const int r = tid & 63, t = tid >> 6;     // selection row / col-phase
    const int rbase = (w & 1) * 32;           // wave's row half
    const int cb32  = (w >> 1) * 32;          // wave's col half

    const unsigned short* Xhb = Xh + (size_t)b * N_PTS * strideX;
    const unsigned short* Xlb = Xl + (size_t)b * N_PTS * strideX;
    const float* sqb = sq + (size_t)b * N_PTS;

    // A fragments (registers): rows row0+rbase+l31, k = ks*16 + lh*8 + j
    short8 ah[KS16], al[KS16];
    #pragma unroll
    for (int ks = 0; ks < KS16; ++ks) {
        size_t o = (size_t)(row0 + rbase + l31) * strideX + ks * 16 + lh * 8;
        ah[ks] = *(const short8*)(Xhb + o);
        al[ks] = *(const short8*)(Xlb + o);
    }

    // per-thread top-20: exact fp32 score + full index, ascending by (val,idx)
    float fv[KNN]; int fi[KNN];
    #pragma unroll
    for (int p = 0; p < KNN; ++p) { fv[p] = INFINITY; fi[p] = 0x7FFFFFFF; }
    thrT[tid] = INFINITY;

    for (int c0 = cs0; c0 < cs0 + CHALF; c0 += 64) {
        __syncthreads();
        // stage B tile: slot tt (linear -> conflict-free stores) holds
        // chunk (col = tt/C8, kc_global = (tt%C8) ^ (col&XK))
        #pragma unroll
        for (int it = 0; it < NIT; ++it) {
            int tt = tid + it * 256;
            int col = tt / C8, kcs = tt % C8;
            int kcg = kcs ^ (col & XK);
            size_t o = (size_t)(c0 + col) * strideX + kcg * 8;
            *(short8*)&BhS[tt * 8] = *(const short8*)(Xhb + o);
            *(short8*)&BlS[tt * 8] = *(const short8*)(Xlb + o);
        }
        if (tid < 64) sqs[tid] = sqb[c0 + tid];
        __syncthreads();

        float16v acc = {};

        const int colL = cb32 + l31;
        const int cbase_us = colL * DPAD;
        #pragma unroll
        for (int ks = 0; ks < KS16; ++ks) {
            int ch = ((ks * 2 + lh) ^ (colL & XK)) * 8;
            short8 bh = *(const short8*)&BhS[cbase_us + ch];
            short8 bl = *(const short8*)&BlS[cbase_us + ch];
            acc = __builtin_amdgcn_mfma_f32_32x32x16_bf16(ah[ks], bh, acc, 0, 0, 0);
            acc = __builtin_amdgcn_mfma_f32_32x32x16_bf16(al[ks], bh, acc, 0, 0, 0);
            acc = __builtin_amdgcn_mfma_f32_32x32x16_bf16(ah[ks], bl, acc, 0, 0, 0);
        }

        // epilogue: Sf[row][(col&3)*16 + (col>>2)] = sq[col] - 2*dot
        // C layout (32x32): col = lane&31, row = (reg&3) + 8*(reg>>2) + 4*(lane>>5)
        {
            float sc = sqs[colL];
            int pos = (colL & 3) * 16 + (colL >> 2);
            #pragma unroll
            for (int reg = 0; reg < 16; ++reg) {
                int rowL = rbase + (reg & 3) + 8 * (reg >> 2) + 4 * lh;
                Sf[rowL * 66 + pos] = sc - 2.f * acc[reg];
            }
        }
        __syncthreads();

        // shared row threshold (deterministic: published last iter, two
        // barriers ago). Every published fv[19] >= row's final 20th value,
        // so skipping v > fT is exact; v == fT still passes -> tie-safe.
        float fT = fminf(fminf(thrT[r], thrT[64 + r]),
                         fminf(thrT[128 + r], thrT[192 + r]));

        // selection: thread (r,t) scans candidates col = c0 + 4*jj + t
        const int sbase = r * 66 + t * 16;
        unsigned mask = 0;
        {
            float f19 = fv[KNN - 1];
            float2v c2[8];
            #pragma unroll
            for (int u = 0; u < 8; ++u) c2[u] = *(const float2v*)&Sf[sbase + 2 * u];
            #pragma unroll
            for (int u = 0; u < 8; ++u) {
                if (c2[u][0] < f19 && c2[u][0] <= fT) mask |= (1u << (2 * u));
                if (c2[u][1] < f19 && c2[u][1] <= fT) mask |= (1u << (2 * u + 1));
            }
        }
        while (mask) {
            int jj = __ffs(mask) - 1;
            mask &= mask - 1;
            float v = Sf[sbase + jj];
            if (v < fv[KNN - 1]) {     // strict: earlier (lower idx) wins ties
                fv[KNN - 1] = v;
                fi[KNN - 1] = c0 + (jj << 2) + t;
                #pragma unroll
                for (int p = KNN - 1; p > 0; --p) {
                    float va = fv[p - 1], vb = fv[p];
                    int   ia = fi[p - 1], ic = fi[p];
                    bool sw = vb < va;
                    fv[p - 1] = sw ? vb : va; fv[p] = sw ? va : vb;
                    fi[p - 1] = sw ? ic : ia; fi[p] = sw ? ia : ic;
                }
            }
        }

        // publish own threshold (read next iter after two barriers)
        thrT[t * 64 + r] = fv[KNN - 1];
    }
    __syncthreads();

    // dump slices t=1..3, lex-merge on threads 0..63
    if (t > 0) {
        #pragma unroll
        for (int p = 0; p < KNN; ++p) {
            kb[r * 61 + (t - 1) * KNN + p] = fv[p];
            ib[r * 61 + (t - 1) * KNN + p] = (unsigned)fi[p];
        }
    }
    __syncthreads();
    if (tid < 64) {
        #pragma unroll 1
        for (int qq = 0; qq < 3 * KNN; ++qq) {
            float    v  = kb[tid * 61 + qq];
            unsigned ii = ib[tid * 61 + qq];
            bool ins = (v < fv[KNN - 1]) ||
                       (v == fv[KNN - 1] && (int)ii < fi[KNN - 1]);
            if (ins) {
                fv[KNN - 1] = v; fi[KNN - 1] = (int)ii;
                #pragma unroll
                for (int p = KNN - 1; p > 0; --p) {
                    float va = fv[p - 1], vb = fv[p];
                    int   ia = fi[p - 1], ic = fi[p];
                    bool sw = (vb < va) || (vb == va && ic < ia);
                    fv[p - 1] = sw ? vb : va; fv[p] = sw ? va : vb;
                    fi[p - 1] = sw ? ic : ia; fi[p] = sw ? ia : ic;
                }
            }
        }
        size_t pb = ((size_t)(b * N_PTS + row0 + tid) * NSPLIT + sidx) * KNN;
        #pragma unroll
        for (int p = 0; p < KNN; ++p) { pv[pb + p] = fv[p]; pi[pb + p] = fi[p]; }
    }
}

// ---------------------------------------------------------------------------
// merge the NSPLIT sorted partial top-20 lists per row -> final 20 indices.
// Two-pointer lex merge; disjoint candidate ranges so (val,idx) order is
// exactly the unsplit streaming result.
__global__ void knn_merge(const float* __restrict__ pv, const int* __restrict__ pi,
                          int* __restrict__ idxout) {
    int row = blockIdx.x * blockDim.x + threadIdx.x;
    if (row >= M_ROWS) return;
    const float* va = pv + (size_t)row * NSPLIT * KNN;
    const float* vb = va + KNN;
    const int*   ja = pi + (size_t)row * NSPLIT * KNN;
    const int*   jb = ja + KNN;
    int* op = idxout + (size_t)row * KNN;
    int a = 0, bq = 0;
    #pragma unroll 1
    for (int p = 0; p < KNN; ++p) {
        bool av = a < KNN, bv = bq < KNN;
        float fa = av ? va[a] : INFINITY;
        float fb = bv ? vb[bq] : INFINITY;
        int   ia = av ? ja[a] : 0x7FFFFFFF;
        int   ibx = bv ? jb[bq] : 0x7FFFFFFF;
        bool takeA = av && (!bv || fa < fb || (fa == fb && ia < ibx));
        op[p] = takeA ? ia : ibx;
        if (takeA) ++a; else ++bq;
    }
}

// ---------------------------------------------------------------------------
// MFMA feature GEMM: out[m,c] = sum_k A[m,k]*W[c,k], bf16 hi/lo 3-pass.
__launch_bounds__(256)
__global__ void fgemm(const unsigned short* __restrict__ Ah, const unsigned short* __restrict__ Al,
                      int strideA, int K,
                      const unsigned short* __restrict__ Wh, const unsigned short* __restrict__ Wl,
                      int C, float* __restrict__ out, int fuse_bn,
                      const float* __restrict__ g, const float* __restrict__ beta) {
    __shared__ unsigned short AhS[128 * 40];
    __shared__ unsigned short AlS[128 * 40];
    __shared__ unsigned short BhS[128 * 40];
    __shared__ unsigned short BlS[128 * 40];

    const int c0 = blockIdx.x * 128;
    const int m0 = blockIdx.y * 128;
    const int tid = threadIdx.x;
    const int w = tid >> 6, lane = tid & 63;
    const int n = lane & 15, q = lane >> 4;

    float4v acc[2][8];
    #pragma unroll
    for (int rt = 0; rt < 2; ++rt)
        #pragma unroll
        for (int ct = 0; ct < 8; ++ct) acc[rt][ct] = (float4v){0.f, 0.f, 0.f, 0.f};

    for (int kk = 0; kk < K; kk += 32) {
        __syncthreads();
        for (int tt = tid; tt < 512; tt += 256) {
            int rr = tt >> 2, c8 = tt & 3;
            size_t oa = (size_t)(m0 + rr) * strideA + kk + c8 * 8;
            *(short8*)&AhS[rr * 40 + c8 * 8] = *(const short8*)(Ah + oa);
            *(short8*)&AlS[rr * 40 + c8 * 8] = *(const short8*)(Al + oa);
            size_t ob = (size_t)(c0 + rr) * K + kk + c8 * 8;
            *(short8*)&BhS[rr * 40 + c8 * 8] = *(const short8*)(Wh + ob);
            *(short8*)&BlS[rr * 40 + c8 * 8] = *(const short8*)(Wl + ob);
        }
        __syncthreads();

        short8 af[2][2];
        #pragma unroll
        for (int rt = 0; rt < 2; ++rt) {
            af[rt][0] = *(const short8*)&AhS[(w * 32 + rt * 16 + n) * 40 + q * 8];
            af[rt][1] = *(const short8*)&AlS[(w * 32 + rt * 16 + n) * 40 + q * 8];
        }
        #pragma unroll
        for (int ct = 0; ct < 8; ++ct) {
            short8 bh = *(const short8*)&BhS[(ct * 16 + n) * 40 + q * 8];
            short8 bl = *(const short8*)&BlS[(ct * 16 + n) * 40 + q * 8];
            #pragma unroll
            for (int rt = 0; rt < 2; ++rt) {
                acc[rt][ct] = __builtin_amdgcn_mfma_f32_16x16x32_bf16(af[rt][0], bh, acc[rt][ct], 0, 0, 0);
                acc[rt][ct] = __builtin_amdgcn_mfma_f32_16x16x32_bf16(af[rt][1], bh, acc[rt][ct], 0, 0, 0);
                acc[rt][ct] = __builtin_amdgcn_mfma_f32_16x16x32_bf16(af[rt][0], bl, acc[rt][ct], 0, 0, 0);
            }
        }
    }

    #pragma unroll
    for (int rt = 0; rt < 2; ++rt)
        #pragma unroll
        for (int ct = 0; ct < 8; ++ct) {
            int c = c0 + ct * 16 + n;
            float sc = 1.f, bt = 0.f;
            if (fuse_bn) { sc = g[c] / sqrtf(1.f + EPS_BN); bt = beta[c]; }
            #pragma unroll
            for (int e = 0; e < 4; ++e) {
                int m = m0 + w * 32 + rt * 16 + q * 4 + e;
                float v = acc[rt][ct][e];
                if (fuse_bn) { v = v * sc + bt; v = (v >= 0.f) ? v : SLOPE * v; }
                out[(size_t)m * C + c] = v;
            }
        }
}

// ---------------------------------------------------------------------------
// EdgeConv max-pool epilogue -> bf16 hi/lo feature rows
__global__ void pool_kernel(const float* __restrict__ zc2, int Co,
                            const int* __restrict__ idx,
                            const float* __restrict__ g, const float* __restrict__ beta,
                            unsigned short* __restrict__ hh, unsigned short* __restrict__ hl,
                            int hoff) {
    int n = blockIdx.x, b = blockIdx.y;
    int o = threadIdx.x;
    size_t bn = (size_t)b * N_PTS + n;
    const int* ip = idx + bn * KNN;
    float zn   = zc2[bn * (size_t)(2 * Co) + o];
    float base = zc2[bn * (size_t)(2 * Co) + Co + o] - zn;
    float m = -INFINITY;
    #pragma unroll
    for (int j = 0; j < KNN; ++j) {
        size_t rr = (size_t)b * N_PTS + ip[j];
        m = fmaxf(m, zc2[rr * (size_t)(2 * Co) + o]);
    }
    float y = m + base;
    float sc = g[o] / sqrtf(1.f + EPS_BN);
    y = y * sc + beta[o];
    y = (y >= 0.f) ? y : SLOPE * y;
    unsigned short h = f2bf(y);
    hh[bn * 512 + hoff + o] = h;
    hl[bn * 512 + hoff + o] = f2bf(y - bf2f(h));
}

// ---------------------------------------------------------------------------
// final global max/mean over N: two-stage (32 chunks of 128 rows)
__global__ void reduce_partial(const float* __restrict__ y5,
                               float* __restrict__ pmax, float* __restrict__ psum) {
    int chunk = blockIdx.x, b = blockIdx.y, c = threadIdx.x;
    float mx = -INFINITY, sm = 0.f;
    for (int qq = 0; qq < 128; ++qq) {
        int n = chunk * 128 + qq;
        float v = y5[((size_t)b * N_PTS + n) * 512 + c];
        mx = fmaxf(mx, v);
        sm += v;
    }
    pmax[((size_t)b * 32 + chunk) * 512 + c] = mx;
    psum[((size_t)b * 32 + chunk) * 512 + c] = sm;
}

__global__ void reduce_final(const float* __restrict__ pmax,
                             const float* __restrict__ psum,
                             float* __restrict__ out) {
    int i = blockIdx.x * blockDim.x + threadIdx.x;
    if (i >= BATCH * 512) return;
    int b = i / 512, c = i % 512;
    float mx = -INFINITY, sm = 0.f;
    for (int qq = 0; qq < 32; ++qq) {
        mx = fmaxf(mx, pmax[((size_t)b * 32 + qq) * 512 + c]);
        sm += psum[((size_t)b * 32 + qq) * 512 + c];
    }
    out[(size_t)b * 1024 + c] = mx;
    out[(size_t)b * 1024 + 512 + c] = sm * (1.f / 4096.f);
}

// ---------------------------------------------------------------------------
extern "C" void kernel_launch(void* const* d_in, const int* in_sizes, int n_in,
                              void* d_out, int out_size, void* d_ws, size_t ws_size,
                              hipStream_t stream) {
    const float* x = (const float*)d_in[0];
    const float* W[5], *gg[5], *bb[5];
    for (int i = 0; i < 5; ++i) {
        W[i]  = (const float*)d_in[2 + 3 * i];
        gg[i] = (const float*)d_in[3 + 3 * i];
        bb[i] = (const float*)d_in[4 + 3 * i];
    }
    float* outp = (float*)d_out;

    char* wsb = (char*)d_ws;
    size_t off = 0;
    unsigned short* x1h = (unsigned short*)(wsb + off); off += (size_t)M_ROWS * 32 * 2;
    unsigned short* x1l = (unsigned short*)(wsb + off); off += (size_t)M_ROWS * 32 * 2;
    float* sq = (float*)(wsb + off); off += (size_t)M_ROWS * 4;
    int*   idx = (int*)(wsb + off); off += (size_t)M_ROWS * KNN * 4;
    unsigned short* Wh = (unsigned short*)(wsb + off); off += (size_t)512 * 512 * 2;
    unsigned short* Wl = (unsigned short*)(wsb + off); off += (size_t)512 * 512 * 2;
    unsigned short* hh = (unsigned short*)(wsb + off); off += (size_t)M_ROWS * 512 * 2;
    unsigned short* hl = (unsigned short*)(wsb + off); off += (size_t)M_ROWS * 512 * 2;
    float* zc2 = (float*)(wsb + off); off += (size_t)M_ROWS * 512 * 4;
    float* pmx = (float*)(wsb + off); off += (size_t)BATCH * 32 * 512 * 4;
    float* psm = (float*)(wsb + off); off += (size_t)BATCH * 32 * 512 * 4;
    float* pv  = (float*)(wsb + off); off += (size_t)M_ROWS * NSPLIT * KNN * 4;
    int*   pi  = (int*)(wsb + off);   off += (size_t)M_ROWS * NSPLIT * KNN * 4;
    (void)ws_size; (void)in_sizes; (void)n_in; (void)out_size;

    convert_x1<<<(M_ROWS + 255) / 256, 256, 0, stream>>>(x, x1h, x1l, sq);

    struct L { int D, Co, KP, hoff; };
    const L layers[4] = { {3, 64, 32, 0}, {64, 64, 64, 64}, {64, 128, 64, 128}, {128, 256, 128, 256} };

    for (int li = 0; li < 4; ++li) {
        const L& ly = layers[li];
        const unsigned short* Ahp;
        const unsigned short* Alp;
        int strideA;
        if (li == 0) { Ahp = x1h; Alp = x1l; strideA = 32; }
        else {
            int po = layers[li - 1].hoff;
            Ahp = hh + po; Alp = hl + po; strideA = 512;
            sqnorm_hl<<<M_ROWS / 4, 256, 0, stream>>>(Ahp, Alp, ly.D, sq);
        }

        if (li == 0)
            knn_mfma<32><<<dim3(N_PTS / 64, BATCH, NSPLIT), 256, 0, stream>>>(Ahp, Alp, strideA, sq, pv, pi);
        else if (ly.D == 64)
            knn_mfma<64><<<dim3(N_PTS / 64, BATCH, NSPLIT), 256, 0, stream>>>(Ahp, Alp, strideA, sq, pv, pi);
        else
            knn_mfma<128><<<dim3(N_PTS / 64, BATCH, NSPLIT), 256, 0, stream>>>(Ahp, Alp, strideA, sq, pv, pi);
        knn_merge<<<(M_ROWS + 255) / 256, 256, 0, stream>>>(pv, pi, idx);

        repack_edge_split<<<(2 * ly.Co * ly.KP + 255) / 256, 256, 0, stream>>>(
            W[li], ly.Co, ly.D, ly.KP, Wh, Wl);
        fgemm<<<dim3((2 * ly.Co) / 128, M_ROWS / 128), 256, 0, stream>>>(
            Ahp, Alp, strideA, ly.KP, Wh, Wl, 2 * ly.Co, zc2, 0, nullptr, nullptr);
        pool_kernel<<<dim3(N_PTS, BATCH), ly.Co, 0, stream>>>(
            zc2, ly.Co, idx, gg[li], bb[li], hh, hl, ly.hoff);
    }

    // layer 5
    repack_w5_split<<<(512 * 512 + 255) / 256, 256, 0, stream>>>(W[4], Wh, Wl);
    fgemm<<<dim3(4, M_ROWS / 128), 256, 0, stream>>>(
        hh, hl, 512, 512, Wh, Wl, 512, zc2, 1, gg[4], bb[4]);

    reduce_partial<<<dim3(32, BATCH), 512, 0, stream>>>(zc2, pmx, psm);
    reduce_final<<<(BATCH * 512 + 255) / 256, 256, 0, stream>>>(pmx, psm, outp);
}

// Round 4
// 1473.562 us; speedup vs baseline: 1.1506x; 1.1506x over previous
//
#include <hip/hip_runtime.h>
#include <math.h>

#define BATCH 8
#define N_PTS 4096
#define KNN 20
#define EPS_BN 1e-5f
#define SLOPE 0.2f
#define M_ROWS (BATCH * N_PTS)

typedef __attribute__((ext_vector_type(8))) short short8;      // bf16 x8 (4 VGPR)
typedef __attribute__((ext_vector_type(4))) float float4v;     // fp32 x4 acc
typedef __attribute__((ext_vector_type(16))) float float16v;   // fp32 x16 acc

__device__ __forceinline__ unsigned short f2bf(float f) {
    unsigned u = __float_as_uint(f);
    unsigned r = (u + 0x7FFFu + ((u >> 16) & 1u)) >> 16;
    return (unsigned short)r;
}
__device__ __forceinline__ float bf2f(unsigned short h) {
    return __uint_as_float((unsigned)h << 16);
}

// ---------------------------------------------------------------------------
// x (B,3,N) fp32 -> x1h/x1l (M,32) bf16 split (zero-padded), + sq norms
__global__ void convert_x1(const float* __restrict__ x,
                           unsigned short* __restrict__ xh, unsigned short* __restrict__ xl,
                           float* __restrict__ sq) {
    int i = blockIdx.x * blockDim.x + threadIdx.x;
    if (i >= M_ROWS) return;
    int b = i / N_PTS, n = i % N_PTS;
    float v[3], s = 0.f;
    #pragma unroll
    for (int d = 0; d < 3; ++d) {
        v[d] = x[((size_t)b * 3 + d) * N_PTS + n];
        s += v[d] * v[d];
    }
    sq[i] = s;
    #pragma unroll
    for (int d = 0; d < 32; ++d) {
        float f = (d < 3) ? v[d] : 0.f;
        unsigned short h = f2bf(f);
        xh[(size_t)i * 32 + d] = h;
        xl[(size_t)i * 32 + d] = f2bf(f - bf2f(h));
    }
}

// sq norms from bf16 hi/lo feature rows (stride 512)
__global__ void sqnorm_hl(const unsigned short* __restrict__ hh,
                          const unsigned short* __restrict__ hl,
                          int D, float* __restrict__ sq) {
    int w = threadIdx.x >> 6, lane = threadIdx.x & 63;
    int row = blockIdx.x * 4 + w;
    if (row >= M_ROWS) return;
    const unsigned short* ph = hh + (size_t)row * 512;
    const unsigned short* pl = hl + (size_t)row * 512;
    float s = 0.f;
    for (int d = lane; d < D; d += 64) {
        float v = bf2f(ph[d]) + bf2f(pl[d]);
        s += v * v;
    }
    #pragma unroll
    for (int off = 32; off > 0; off >>= 1) s += __shfl_down(s, off, 64);
    if (lane == 0) sq[row] = s;
}

// ---------------------------------------------------------------------------
// weight repacks -> bf16 hi/lo, B-operand layout [C][KP] (k contiguous)
__global__ void repack_edge_split(const float* __restrict__ W, int Co, int D, int KP,
                                  unsigned short* __restrict__ Wh, unsigned short* __restrict__ Wl) {
    int i = blockIdx.x * blockDim.x + threadIdx.x;
    int tot = 2 * Co * KP;
    if (i >= tot) return;
    int r = i / KP, d = i % KP;
    float v = 0.f;
    if (d < D) v = (r < Co) ? W[(size_t)r * 2 * D + d] : W[(size_t)(r - Co) * 2 * D + D + d];
    unsigned short h = f2bf(v);
    Wh[i] = h; Wl[i] = f2bf(v - bf2f(h));
}

__global__ void repack_w5_split(const float* __restrict__ W,
                                unsigned short* __restrict__ Wh, unsigned short* __restrict__ Wl) {
    int i = blockIdx.x * blockDim.x + threadIdx.x;
    if (i >= 512 * 512) return;
    float v = W[i];
    unsigned short h = f2bf(v);
    Wh[i] = h; Wl[i] = f2bf(v - bf2f(h));
}

// ---------------------------------------------------------------------------
// MFMA KNN v10: wave-autonomous, ZERO barriers in the main loop.
// Rationale: v6-v9 showed per-tile wall (~12.4k cyc) >> per-tile work (~2k);
// the 3-barrier lockstep serialized max(load)+max(mfma)+max(divergent select)
// across 4 waves every tile. Here each wave runs its own pipeline:
//  * B fragments loaded DIRECTLY from global (the mfma_32x32x16 B layout is
//    a contiguous short8 per lane: col=lane&31, k=(lane>>5)*8+j) - no LDS
//    staging, no staging barriers, no staging bank conflicts.
//  * wave-private Sf[32][33] transposes scores (write: conflict-free,
//    read: 2-way = free); cross-lane within one wave -> lgkmcnt only.
//  * per-row threshold pair-shared via shfl_xor(32) (partner lane holds the
//    same row's other col-slice). Exact: published f19 >= row's final 20th.
//  * barriers only at the final 4-list merge (2 per kernel, was 192).
// Wave w: rows (w&1)*32 + l31 of the block's 64-row tile, cols
// (w>>1)*32 + l31 of each 64-col candidate tile. Each lane streams 1024
// candidates -> sorted (val,idx) top-20; merge = exact unsplit semantics.
// grid: (N/64, B), block 256.
template<int DPAD>
__launch_bounds__(256, 2)
__global__ void knn_mfma(const unsigned short* __restrict__ Xh,
                         const unsigned short* __restrict__ Xl,
                         int strideX,
                         const float* __restrict__ sq, int* __restrict__ idxout) {
    constexpr int KS16 = DPAD / 16;           // mfma k-steps (K=16)
    constexpr int SST  = 33;                  // Sf stride (conflict-free both phases)
    constexpr size_t POOL = (size_t)64 * 4 * KNN * 4 * 2;   // merge dominates (40960)
    __shared__ __align__(16) char smem[POOL];
    float* Sfw = (float*)smem + (size_t)(threadIdx.x >> 6) * 32 * SST;  // wave-private
    float*    kb = (float*)smem;              // merge: [64 rows][4 slots][20] vals
    unsigned* ib = (unsigned*)(kb + 64 * 4 * KNN);

    const int b = blockIdx.y;
    const int row0 = blockIdx.x * 64;
    const int tid = threadIdx.x;
    const int w = tid >> 6, lane = tid & 63;
    const int l31 = lane & 31, lh = lane >> 5;
    const int rbase = (w & 1) * 32;           // wave's row half
    const int cb32  = (w >> 1) * 32;          // wave's col half

    const unsigned short* Xhb = Xh + (size_t)b * N_PTS * strideX;
    const unsigned short* Xlb = Xl + (size_t)b * N_PTS * strideX;
    const float* sqb = sq + (size_t)b * N_PTS;

    // A fragments (registers): rows row0+rbase+l31, k = ks*16 + lh*8 + j
    short8 ah[KS16], al[KS16];
    #pragma unroll
    for (int ks = 0; ks < KS16; ++ks) {
        size_t o = (size_t)(row0 + rbase + l31) * strideX + ks * 16 + lh * 8;
        ah[ks] = *(const short8*)(Xhb + o);
        al[ks] = *(const short8*)(Xlb + o);
    }

    // per-lane B-fragment base pointers (advance by 64*strideX per tile)
    const unsigned short* pBh = Xhb + (size_t)(cb32 + l31) * strideX + lh * 8;
    const unsigned short* pBl = Xlb + (size_t)(cb32 + l31) * strideX + lh * 8;
    const float* psq = sqb + cb32 + l31;

    // per-lane top-20: exact fp32 score + full index, ascending by (val,idx)
    float fv[KNN]; int fi[KNN];
    #pragma unroll
    for (int p = 0; p < KNN; ++p) { fv[p] = INFINITY; fi[p] = 0x7FFFFFFF; }

    for (int c0 = 0; c0 < N_PTS; c0 += 64) {
        // B fragments for this tile: direct global loads (L2-resident)
        short8 bh[KS16], bl[KS16];
        #pragma unroll
        for (int ks = 0; ks < KS16; ++ks) {
            bh[ks] = *(const short8*)(pBh + (size_t)c0 * strideX + ks * 16);
            bl[ks] = *(const short8*)(pBl + (size_t)c0 * strideX + ks * 16);
        }
        float sc = psq[c0];

        float16v a0 = {}, a1 = {}, a2 = {};
        #pragma unroll
        for (int ks = 0; ks < KS16; ++ks) {
            if (KS16 <= 4) {            // 3 independent chains (ILP), D<=64
                a0 = __builtin_amdgcn_mfma_f32_32x32x16_bf16(ah[ks], bh[ks], a0, 0, 0, 0);
                a1 = __builtin_amdgcn_mfma_f32_32x32x16_bf16(al[ks], bh[ks], a1, 0, 0, 0);
                a2 = __builtin_amdgcn_mfma_f32_32x32x16_bf16(ah[ks], bl[ks], a2, 0, 0, 0);
            } else {                    // single chain, save VGPRs, D=128
                a0 = __builtin_amdgcn_mfma_f32_32x32x16_bf16(ah[ks], bh[ks], a0, 0, 0, 0);
                a0 = __builtin_amdgcn_mfma_f32_32x32x16_bf16(al[ks], bh[ks], a0, 0, 0, 0);
                a0 = __builtin_amdgcn_mfma_f32_32x32x16_bf16(ah[ks], bl[ks], a0, 0, 0, 0);
            }
        }

        // transpose scores into wave-private Sf: Sf[rowLocal][colLocal]
        // C layout (32x32): col = lane&31, row = (reg&3) + 8*(reg>>2) + 4*(lane>>5)
        #pragma unroll
        for (int reg = 0; reg < 16; ++reg) {
            int rowL = (reg & 3) + 8 * (reg >> 2) + 4 * lh;
            float v = (KS16 <= 4) ? (a0[reg] + a1[reg] + a2[reg]) : a0[reg];
            Sfw[rowL * SST + l31] = sc - 2.f * v;
        }
        // wave-internal LDS visibility (no barrier: private buffer)
        asm volatile("s_waitcnt lgkmcnt(0)" ::: "memory");

        // shared row threshold: partner lane (lane^32) holds the same row's
        // other 16-col slice. Any current f19 >= row's final 20th value, so
        // skipping v > fT is exact; v == own f19 correctly rejected (ties
        // resolved by streaming order = ascending idx).
        float f19 = fv[KNN - 1];
        float fT = fminf(f19, __shfl_xor(f19, 32, 64));

        // selection: lane scans row l31, local cols lh*16 + [0,16)
        const int sbase = l31 * SST + lh * 16;
        unsigned mask = 0;
        #pragma unroll
        for (int jj = 0; jj < 16; ++jj) {
            float v = Sfw[sbase + jj];
            if (v < f19 && v <= fT) mask |= (1u << jj);
        }
        while (mask) {
            int jj = __ffs(mask) - 1;
            mask &= mask - 1;
            float v = Sfw[sbase + jj];
            if (v < fv[KNN - 1]) {     // strict: earlier (lower idx) wins ties
                fv[KNN - 1] = v;
                fi[KNN - 1] = c0 + cb32 + lh * 16 + jj;
                #pragma unroll
                for (int p = KNN - 1; p > 0; --p) {
                    float va = fv[p - 1], vb = fv[p];
                    int   ia = fi[p - 1], ic = fi[p];
                    bool sw = vb < va;
                    fv[p - 1] = sw ? vb : va; fv[p] = sw ? va : vb;
                    fi[p - 1] = sw ? ic : ia; fi[p] = sw ? ia : ic;
                }
            }
        }
    }

    // ---- final merge: 4 sorted lists per row (2 lanes x 2 col-half waves)
    __syncthreads();                           // everyone done with Sf pool
    {
        int rowb = rbase + l31;                // block-local row 0..63
        int slot = (w >> 1) * 2 + lh;          // 0..3
        int base = (rowb * 4 + slot) * KNN;
        #pragma unroll
        for (int p = 0; p < KNN; ++p) { kb[base + p] = fv[p]; ib[base + p] = (unsigned)fi[p]; }
    }
    __syncthreads();
    if (tid < 64) {
        int base = tid * 4 * KNN;
        #pragma unroll
        for (int p = 0; p < KNN; ++p) { fv[p] = kb[base + p]; fi[p] = (int)ib[base + p]; }
        #pragma unroll 1
        for (int qq = 0; qq < 3 * KNN; ++qq) {
            float    v  = kb[base + KNN + qq];
            unsigned ii = ib[base + KNN + qq];
            bool ins = (v < fv[KNN - 1]) ||
                       (v == fv[KNN - 1] && (int)ii < fi[KNN - 1]);
            if (ins) {
                fv[KNN - 1] = v; fi[KNN - 1] = (int)ii;
                #pragma unroll
                for (int p = KNN - 1; p > 0; --p) {
                    float va = fv[p - 1], vb = fv[p];
                    int   ia = fi[p - 1], ic = fi[p];
                    bool sw = (vb < va) || (vb == va && ic < ia);
                    fv[p - 1] = sw ? vb : va; fv[p] = sw ? va : vb;
                    fi[p - 1] = sw ? ic : ia; fi[p] = sw ? ia : ic;
                }
            }
        }
        int* op = idxout + ((size_t)(b * N_PTS + row0 + tid)) * KNN;
        #pragma unroll
        for (int p = 0; p < KNN; ++p) op[p] = fi[p];
    }
}

// ---------------------------------------------------------------------------
// MFMA feature GEMM: out[m,c] = sum_k A[m,k]*W[c,k], bf16 hi/lo 3-pass.
__launch_bounds__(256)
__global__ void fgemm(const unsigned short* __restrict__ Ah, const unsigned short* __restrict__ Al,
                      int strideA, int K,
                      const unsigned short* __restrict__ Wh, const unsigned short* __restrict__ Wl,
                      int C, float* __restrict__ out, int fuse_bn,
                      const float* __restrict__ g, const float* __restrict__ beta) {
    __shared__ unsigned short AhS[128 * 40];
    __shared__ unsigned short AlS[128 * 40];
    __shared__ unsigned short BhS[128 * 40];
    __shared__ unsigned short BlS[128 * 40];

    const int c0 = blockIdx.x * 128;
    const int m0 = blockIdx.y * 128;
    const int tid = threadIdx.x;
    const int w = tid >> 6, lane = tid & 63;
    const int n = lane & 15, q = lane >> 4;

    float4v acc[2][8];
    #pragma unroll
    for (int rt = 0; rt < 2; ++rt)
        #pragma unroll
        for (int ct = 0; ct < 8; ++ct) acc[rt][ct] = (float4v){0.f, 0.f, 0.f, 0.f};

    for (int kk = 0; kk < K; kk += 32) {
        __syncthreads();
        for (int tt = tid; tt < 512; tt += 256) {
            int rr = tt >> 2, c8 = tt & 3;
            size_t oa = (size_t)(m0 + rr) * strideA + kk + c8 * 8;
            *(short8*)&AhS[rr * 40 + c8 * 8] = *(const short8*)(Ah + oa);
            *(short8*)&AlS[rr * 40 + c8 * 8] = *(const short8*)(Al + oa);
            size_t ob = (size_t)(c0 + rr) * K + kk + c8 * 8;
            *(short8*)&BhS[rr * 40 + c8 * 8] = *(const short8*)(Wh + ob);
            *(short8*)&BlS[rr * 40 + c8 * 8] = *(const short8*)(Wl + ob);
        }
        __syncthreads();

        short8 af[2][2];
        #pragma unroll
        for (int rt = 0; rt < 2; ++rt) {
            af[rt][0] = *(const short8*)&AhS[(w * 32 + rt * 16 + n) * 40 + q * 8];
            af[rt][1] = *(const short8*)&AlS[(w * 32 + rt * 16 + n) * 40 + q * 8];
        }
        #pragma unroll
        for (int ct = 0; ct < 8; ++ct) {
            short8 bh = *(const short8*)&BhS[(ct * 16 + n) * 40 + q * 8];
            short8 bl = *(const short8*)&BlS[(ct * 16 + n) * 40 + q * 8];
            #pragma unroll
            for (int rt = 0; rt < 2; ++rt) {
                acc[rt][ct] = __builtin_amdgcn_mfma_f32_16x16x32_bf16(af[rt][0], bh, acc[rt][ct], 0, 0, 0);
                acc[rt][ct] = __builtin_amdgcn_mfma_f32_16x16x32_bf16(af[rt][1], bh, acc[rt][ct], 0, 0, 0);
                acc[rt][ct] = __builtin_amdgcn_mfma_f32_16x16x32_bf16(af[rt][0], bl, acc[rt][ct], 0, 0, 0);
            }
        }
    }

    #pragma unroll
    for (int rt = 0; rt < 2; ++rt)
        #pragma unroll
        for (int ct = 0; ct < 8; ++ct) {
            int c = c0 + ct * 16 + n;
            float sc = 1.f, bt = 0.f;
            if (fuse_bn) { sc = g[c] / sqrtf(1.f + EPS_BN); bt = beta[c]; }
            #pragma unroll
            for (int e = 0; e < 4; ++e) {
                int m = m0 + w * 32 + rt * 16 + q * 4 + e;
                float v = acc[rt][ct][e];
                if (fuse_bn) { v = v * sc + bt; v = (v >= 0.f) ? v : SLOPE * v; }
                out[(size_t)m * C + c] = v;
            }
        }
}

// ---------------------------------------------------------------------------
// EdgeConv max-pool epilogue -> bf16 hi/lo feature rows
__global__ void pool_kernel(const float* __restrict__ zc2, int Co,
                            const int* __restrict__ idx,
                            const float* __restrict__ g, const float* __restrict__ beta,
                            unsigned short* __restrict__ hh, unsigned short* __restrict__ hl,
                            int hoff) {
    int n = blockIdx.x, b = blockIdx.y;
    int o = threadIdx.x;
    size_t bn = (size_t)b * N_PTS + n;
    const int* ip = idx + bn * KNN;
    float zn   = zc2[bn * (size_t)(2 * Co) + o];
    float base = zc2[bn * (size_t)(2 * Co) + Co + o] - zn;
    float m = -INFINITY;
    #pragma unroll
    for (int j = 0; j < KNN; ++j) {
        size_t rr = (size_t)b * N_PTS + ip[j];
        m = fmaxf(m, zc2[rr * (size_t)(2 * Co) + o]);
    }
    float y = m + base;
    float sc = g[o] / sqrtf(1.f + EPS_BN);
    y = y * sc + beta[o];
    y = (y >= 0.f) ? y : SLOPE * y;
    unsigned short h = f2bf(y);
    hh[bn * 512 + hoff + o] = h;
    hl[bn * 512 + hoff + o] = f2bf(y - bf2f(h));
}

// ---------------------------------------------------------------------------
// final global max/mean over N: two-stage (32 chunks of 128 rows)
__global__ void reduce_partial(const float* __restrict__ y5,
                               float* __restrict__ pmax, float* __restrict__ psum) {
    int chunk = blockIdx.x, b = blockIdx.y, c = threadIdx.x;
    float mx = -INFINITY, sm = 0.f;
    for (int qq = 0; qq < 128; ++qq) {
        int n = chunk * 128 + qq;
        float v = y5[((size_t)b * N_PTS + n) * 512 + c];
        mx = fmaxf(mx, v);
        sm += v;
    }
    pmax[((size_t)b * 32 + chunk) * 512 + c] = mx;
    psum[((size_t)b * 32 + chunk) * 512 + c] = sm;
}

__global__ void reduce_final(const float* __restrict__ pmax,
                             const float* __restrict__ psum,
                             float* __restrict__ out) {
    int i = blockIdx.x * blockDim.x + threadIdx.x;
    if (i >= BATCH * 512) return;
    int b = i / 512, c = i % 512;
    float mx = -INFINITY, sm = 0.f;
    for (int qq = 0; qq < 32; ++qq) {
        mx = fmaxf(mx, pmax[((size_t)b * 32 + qq) * 512 + c]);
        sm += psum[((size_t)b * 32 + qq) * 512 + c];
    }
    out[(size_t)b * 1024 + c] = mx;
    out[(size_t)b * 1024 + 512 + c] = sm * (1.f / 4096.f);
}

// ---------------------------------------------------------------------------
extern "C" void kernel_launch(void* const* d_in, const int* in_sizes, int n_in,
                              void* d_out, int out_size, void* d_ws, size_t ws_size,
                              hipStream_t stream) {
    const float* x = (const float*)d_in[0];
    const float* W[5], *gg[5], *bb[5];
    for (int i = 0; i < 5; ++i) {
        W[i]  = (const float*)d_in[2 + 3 * i];
        gg[i] = (const float*)d_in[3 + 3 * i];
        bb[i] = (const float*)d_in[4 + 3 * i];
    }
    float* outp = (float*)d_out;

    char* wsb = (char*)d_ws;
    size_t off = 0;
    unsigned short* x1h = (unsigned short*)(wsb + off); off += (size_t)M_ROWS * 32 * 2;
    unsigned short* x1l = (unsigned short*)(wsb + off); off += (size_t)M_ROWS * 32 * 2;
    float* sq = (float*)(wsb + off); off += (size_t)M_ROWS * 4;
    int*   idx = (int*)(wsb + off); off += (size_t)M_ROWS * KNN * 4;
    unsigned short* Wh = (unsigned short*)(wsb + off); off += (size_t)512 * 512 * 2;
    unsigned short* Wl = (unsigned short*)(wsb + off); off += (size_t)512 * 512 * 2;
    unsigned short* hh = (unsigned short*)(wsb + off); off += (size_t)M_ROWS * 512 * 2;
    unsigned short* hl = (unsigned short*)(wsb + off); off += (size_t)M_ROWS * 512 * 2;
    float* zc2 = (float*)(wsb + off); off += (size_t)M_ROWS * 512 * 4;
    float* pmx = (float*)(wsb + off); off += (size_t)BATCH * 32 * 512 * 4;
    float* psm = (float*)(wsb + off); off += (size_t)BATCH * 32 * 512 * 4;
    (void)ws_size; (void)in_sizes; (void)n_in; (void)out_size;

    convert_x1<<<(M_ROWS + 255) / 256, 256, 0, stream>>>(x, x1h, x1l, sq);

    struct L { int D, Co, KP, hoff; };
    const L layers[4] = { {3, 64, 32, 0}, {64, 64, 64, 64}, {64, 128, 64, 128}, {128, 256, 128, 256} };

    for (int li = 0; li < 4; ++li) {
        const L& ly = layers[li];
        const unsigned short* Ahp;
        const unsigned short* Alp;
        int strideA;
        if (li == 0) { Ahp = x1h; Alp = x1l; strideA = 32; }
        else {
            int po = layers[li - 1].hoff;
            Ahp = hh + po; Alp = hl + po; strideA = 512;
            sqnorm_hl<<<M_ROWS / 4, 256, 0, stream>>>(Ahp, Alp, ly.D, sq);
        }

        if (li == 0)
            knn_mfma<32><<<dim3(N_PTS / 64, BATCH), 256, 0, stream>>>(Ahp, Alp, strideA, sq, idx);
        else if (ly.D == 64)
            knn_mfma<64><<<dim3(N_PTS / 64, BATCH), 256, 0, stream>>>(Ahp, Alp, strideA, sq, idx);
        else
            knn_mfma<128><<<dim3(N_PTS / 64, BATCH), 256, 0, stream>>>(Ahp, Alp, strideA, sq, idx);

        repack_edge_split<<<(2 * ly.Co * ly.KP + 255) / 256, 256, 0, stream>>>(
            W[li], ly.Co, ly.D, ly.KP, Wh, Wl);
        fgemm<<<dim3((2 * ly.Co) / 128, M_ROWS / 128), 256, 0, stream>>>(
            Ahp, Alp, strideA, ly.KP, Wh, Wl, 2 * ly.Co, zc2, 0, nullptr, nullptr);
        pool_kernel<<<dim3(N_PTS, BATCH), ly.Co, 0, stream>>>(
            zc2, ly.Co, idx, gg[li], bb[li], hh, hl, ly.hoff);
    }

    // layer 5
    repack_w5_split<<<(512 * 512 + 255) / 256, 256, 0, stream>>>(W[4], Wh, Wl);
    fgemm<<<dim3(4, M_ROWS / 128), 256, 0, stream>>>(
        hh, hl, 512, 512, Wh, Wl, 512, zc2, 1, gg[4], bb[4]);

    reduce_partial<<<dim3(32, BATCH), 512, 0, stream>>>(zc2, pmx, psm);
    reduce_final<<<(BATCH * 512 + 255) / 256, 256, 0, stream>>>(pmx, psm, outp);
}